// Round 15
// baseline (451.287 us; speedup 1.0000x reference)
//
#include <hip/hip_runtime.h>

#define DH 64
#define BN_EPS 1e-5f

typedef _Float16 f16;
typedef _Float16 f16x4 __attribute__((ext_vector_type(4)));
typedef _Float16 f16x8 __attribute__((ext_vector_type(8)));
typedef float f32x4 __attribute__((ext_vector_type(4)));

__global__ __launch_bounds__(256) void k_count(const int* __restrict__ dst,
                                               int* __restrict__ degi, int e) {
  int i = blockIdx.x * 256 + threadIdx.x;
  if (i < e) atomicAdd(&degi[dst[i]], 1);
}

// Per-block scan: local exclusive prefix -> loc (=cursor buf), block total -> partial.
__global__ __launch_bounds__(256) void k_scan1(const int* __restrict__ degi,
    float* __restrict__ dinv, int* __restrict__ loc, int* __restrict__ partial, int n)
{
  const int t = threadIdx.x;
  const int i = blockIdx.x * 256 + t;
  int v = (i < n) ? degi[i] : 0;
  if (i < n) dinv[i] = 1.0f / sqrtf((float)v + 1.0f);
  __shared__ int sc[256];
  sc[t] = v;
  __syncthreads();
  #pragma unroll
  for (int d = 1; d < 256; d <<= 1) {
    int u = (t >= d) ? sc[t - d] : 0;
    __syncthreads();
    sc[t] += u;
    __syncthreads();
  }
  if (i < n) loc[i] = sc[t] - v;              // local exclusive
  if (t == 255) partial[blockIdx.x] = sc[t];  // block total
}

__global__ __launch_bounds__(256) void k_scan2(const int* __restrict__ partial,
    int* __restrict__ loc_cursor, int* __restrict__ off, int n, int e)
{
  const int t = threadIdx.x;
  __shared__ int red[256];
  int s = 0;
  for (int i = t; i < (int)blockIdx.x; i += 256) s += partial[i];
  red[t] = s;
  __syncthreads();
  #pragma unroll
  for (int d = 128; d; d >>= 1) {
    if (t < d) red[t] += red[t + d];
    __syncthreads();
  }
  const int base = red[0];
  const int i = blockIdx.x * 256 + t;
  if (i < n) {
    int o = loc_cursor[i] + base;
    off[i] = o;
    loc_cursor[i] = o;  // becomes the fill cursor
  }
  if (i == n) off[n] = e;
}

__global__ __launch_bounds__(256) void k_fill(const int* __restrict__ src,
    const int* __restrict__ dst, int* __restrict__ cursor,
    int* __restrict__ csr, int e)
{
  int i = blockIdx.x * 256 + threadIdx.x;
  if (i < e) {
    int p = atomicAdd(&cursor[dst[i]], 1);
    csr[p] = src[i];
  }
}

// All three weights transposed+fp16 in one launch; also zero hn row n
// (the dummy row that tail-masked quad gathers read).
__global__ __launch_bounds__(256) void k_wprep(const float* __restrict__ W0,
    const float* __restrict__ W1, const float* __restrict__ W2,
    f16* __restrict__ wt0, f16* __restrict__ wt1, f16* __restrict__ wt2,
    f16* __restrict__ hn_zero_row)
{
  int idx = blockIdx.x * 256 + threadIdx.x;
  if (idx < 128 * DH) {
    int k = idx >> 6, c = idx & 63;
    wt0[(size_t)c * 128 + k] = (f16)W0[idx];
  }
  if (idx < 64 * DH) {
    int k = idx >> 6, c = idx & 63;
    wt1[(size_t)c * 64 + k] = (f16)W1[idx];
    wt2[(size_t)c * 64 + k] = (f16)W2[idx];
  }
  if (idx < DH) hn_zero_row[idx] = (f16)0.f;
}

// ss[c] = gamma/sqrt(var+eps); ss[DH+c] = beta - mu*scale   (from BN stats S)
__global__ __launch_bounds__(64) void k_scaleshift(const float* __restrict__ S,
    const float* __restrict__ gamma, const float* __restrict__ beta,
    float* __restrict__ ss, float inv_n)
{
  int c = threadIdx.x;
  float mu = S[c] * inv_n;
  float var = S[DH + c] * inv_n - mu * mu;
  float scv = gamma[c] / sqrtf(var + BN_EPS);
  ss[c] = scv;
  ss[DH + c] = fmaf(-mu, scv, beta[c]);
}

// MFMA GEMM (validated R10): hn[r][c] = fp16((fp16(X')@Wt^T)[r][c]*dinv[r]).
template<int K, bool APPLY>
__global__ __launch_bounds__(256) void k_mfma(const float* __restrict__ X,
    const f16* __restrict__ Wt, const float* __restrict__ dinv,
    const float* __restrict__ ss, f16* __restrict__ hn, int n)
{
  const int lane = threadIdx.x & 63;
  const int wv = threadIdx.x >> 6;
  const int row0 = (blockIdx.x * 4 + wv) * 16;
  if (row0 >= n) return;
  const int r = lane & 15;
  const int g = lane >> 4;
  const int koff = g * 8;
  constexpr int NS = K / 32;

  f16x8 bfrag[4][NS];
  #pragma unroll
  for (int t = 0; t < 4; t++)
    #pragma unroll
    for (int s = 0; s < NS; s++)
      bfrag[t][s] = *(const f16x8*)(Wt + (size_t)(t * 16 + r) * K + s * 32 + koff);

  int row = row0 + r;
  if (row > n - 1) row = n - 1;
  f16x8 afrag[NS];
  #pragma unroll
  for (int s = 0; s < NS; s++) {
    const float* xp = X + (size_t)row * K + s * 32 + koff;
    f16x8 a;
    #pragma unroll
    for (int j = 0; j < 8; j++) {
      float v = xp[j];
      if (APPLY) {
        int c = s * 32 + koff + j;
        v = fmaxf(0.f, fmaf(v, ss[c], ss[DH + c]));
      }
      a[j] = (f16)v;
    }
    afrag[s] = a;
  }

  f32x4 acc0 = {0.f, 0.f, 0.f, 0.f};
  f32x4 acc1 = acc0, acc2 = acc0, acc3 = acc0;
  #pragma unroll
  for (int s = 0; s < NS; s++) {
    acc0 = __builtin_amdgcn_mfma_f32_16x16x32_f16(afrag[s], bfrag[0][s], acc0, 0, 0, 0);
    acc1 = __builtin_amdgcn_mfma_f32_16x16x32_f16(afrag[s], bfrag[1][s], acc1, 0, 0, 0);
    acc2 = __builtin_amdgcn_mfma_f32_16x16x32_f16(afrag[s], bfrag[2][s], acc2, 0, 0, 0);
    acc3 = __builtin_amdgcn_mfma_f32_16x16x32_f16(afrag[s], bfrag[3][s], acc3, 0, 0, 0);
  }

  #pragma unroll
  for (int reg = 0; reg < 4; reg++) {
    int orow = row0 + g * 4 + reg;
    if (orow < n) {
      float di = dinv[orow];
      f16* hp = hn + (size_t)orow * DH + r;
      hp[0]  = (f16)(acc0[reg] * di);
      hp[16] = (f16)(acc1[reg] * di);
      hp[32] = (f16)(acc2[reg] * di);
      hp[48] = (f16)(acc3[reg] * di);
    }
  }
}

// Fused aggregate + BN-stats, quad-gather form. The aggbn wall is the vmem
// gather-instruction rate (~12G/s chip, measured R4/R7/R10), so pack FOUR
// edges per instruction: lane group g=lane>>4 handles edge j+g; each lane
// loads f16x4 (8B) at col 4*sl, 16 lanes x 8B = one full 128B fp16 row.
// Cross-group combine = shfl_xor(16)+shfl_xor(32). Tail quads read the
// zero row hn[n] via predicated index (no OOB, no extra branch body).
__global__ __launch_bounds__(256) void k_aggbn(const f16* __restrict__ hn,
    const int* __restrict__ off, const int* __restrict__ csr,
    const float* __restrict__ dinv, const float* __restrict__ b,
    float* __restrict__ y, float* __restrict__ S, int n)
{
  const int lane = threadIdx.x & 63;
  const int g = lane >> 4;    // edge slot within quad
  const int sl = lane & 15;   // column quad: cols 4sl..4sl+3
  const int w = threadIdx.x >> 6;
  const int wid = __builtin_amdgcn_readfirstlane(blockIdx.x * 4 + w);
  const int nw = gridDim.x * 4;
  f32x4 bias = ((const f32x4*)b)[sl];
  f32x4 s1 = {0.f, 0.f, 0.f, 0.f}, s2 = s1;

  for (int d = wid; d < n; d += nw) {
    f32x4 acc = {0.f, 0.f, 0.f, 0.f};
    f32x4 acc2 = acc;
    if (g == 0) {  // self-loop row
      f16x4 hv = *(const f16x4*)(hn + (size_t)d * DH + sl * 4);
      acc[0] = (float)hv[0]; acc[1] = (float)hv[1];
      acc[2] = (float)hv[2]; acc[3] = (float)hv[3];
    }
    int j = off[d];
    const int end = off[d + 1];
    // 2-quad unroll: 8 edges, 2 independent gathers in flight.
    for (; j + 7 < end; j += 8) {
      int r0 = csr[j + g];
      int r1 = csr[j + 4 + g];
      f16x4 h0 = *(const f16x4*)(hn + (size_t)r0 * DH + sl * 4);
      f16x4 h1 = *(const f16x4*)(hn + (size_t)r1 * DH + sl * 4);
      acc[0] += (float)h0[0]; acc[1] += (float)h0[1];
      acc[2] += (float)h0[2]; acc[3] += (float)h0[3];
      acc2[0] += (float)h1[0]; acc2[1] += (float)h1[1];
      acc2[2] += (float)h1[2]; acc2[3] += (float)h1[3];
    }
    // Tail quads (masked to zero row).
    for (; j < end; j += 4) {
      int r0 = (j + g < end) ? csr[j + g] : n;
      f16x4 h0 = *(const f16x4*)(hn + (size_t)r0 * DH + sl * 4);
      acc[0] += (float)h0[0]; acc[1] += (float)h0[1];
      acc[2] += (float)h0[2]; acc[3] += (float)h0[3];
    }
    acc[0] += acc2[0]; acc[1] += acc2[1]; acc[2] += acc2[2]; acc[3] += acc2[3];
    // Cross-group reduce (4 groups -> all lanes hold full col sums).
    #pragma unroll
    for (int q = 0; q < 4; q++) {
      acc[q] += __shfl_xor(acc[q], 16);
      acc[q] += __shfl_xor(acc[q], 32);
    }
    if (g == 0) {
      float di = dinv[d];
      f32x4 v;
      #pragma unroll
      for (int q = 0; q < 4; q++) v[q] = fmaf(acc[q], di, bias[q]);
      *(f32x4*)(y + (size_t)d * DH + sl * 4) = v;
      #pragma unroll
      for (int q = 0; q < 4; q++) {
        s1[q] += v[q];
        s2[q] = fmaf(v[q], v[q], s2[q]);
      }
    }
  }

  __shared__ float L[8][DH];
  if (g == 0) {
    *(f32x4*)&L[w][sl * 4] = s1;
    *(f32x4*)&L[4 + w][sl * 4] = s2;
  }
  __syncthreads();
  if (threadIdx.x < DH) {
    float t1 = L[0][threadIdx.x] + L[1][threadIdx.x] + L[2][threadIdx.x] + L[3][threadIdx.x];
    float t2 = L[4][threadIdx.x] + L[5][threadIdx.x] + L[6][threadIdx.x] + L[7][threadIdx.x];
    atomicAdd(&S[threadIdx.x], t1);
    atomicAdd(&S[DH + threadIdx.x], t2);
  }
}

// out[r] = sum_c relu(y[r][c]*sc+sh) * Wout[c] + bout
__global__ __launch_bounds__(256) void k_out(const float* __restrict__ y,
    const float* __restrict__ ss, const float* __restrict__ Wout,
    const float* __restrict__ bout, float* __restrict__ out, int n)
{
  const int lane = threadIdx.x & 63;
  const int wid = blockIdx.x * 4 + (threadIdx.x >> 6);
  const int nw = gridDim.x * 4;
  float wv = Wout[lane];
  float sc = ss[lane], sh = ss[DH + lane];
  float bo = bout[0];
  for (int r = wid; r < n; r += nw) {
    float v = fmaxf(0.f, fmaf(y[(size_t)r * DH + lane], sc, sh)) * wv;
    #pragma unroll
    for (int off = 32; off; off >>= 1) v += __shfl_xor(v, off);
    if (lane == 0) out[r] = v + bo;
  }
}

extern "C" void kernel_launch(void* const* d_in, const int* in_sizes, int n_in,
                              void* d_out, int out_size, void* d_ws, size_t ws_size,
                              hipStream_t stream) {
  const float* x     = (const float*)d_in[0];
  const int*   ei    = (const int*)  d_in[1];
  const float* W0    = (const float*)d_in[2];
  const float* b0    = (const float*)d_in[3];
  const float* W1    = (const float*)d_in[4];
  const float* b1    = (const float*)d_in[5];
  const float* W2    = (const float*)d_in[6];
  const float* b2    = (const float*)d_in[7];
  const float* gamma = (const float*)d_in[8];
  const float* beta  = (const float*)d_in[9];
  const float* Wout  = (const float*)d_in[10];
  const float* bout  = (const float*)d_in[11];
  float* out = (float*)d_out;

  const int n = in_sizes[0] / 128;  // d_in = 128
  const int e = in_sizes[1] / 2;
  const int* src = ei;
  const int* dst = ei + e;
  const float inv_n = 1.0f / (float)n;

  const int nblk_scan = (n + 255) / 256;

  // Workspace layout (BYTE offsets, 256B-aligned blocks).
  auto aln = [](size_t v) { return (v + 255) & ~(size_t)255; };
  char* ws = (char*)d_ws;
  size_t o_degi = 0;                                   // int[n]     (zeroed)
  size_t o_S    = o_degi + (size_t)n * 4;              // f32[3*128] (zeroed, adjacent)
  size_t o_part = aln(o_S + 3 * 2 * DH * 4);           // int[nblk_scan]
  size_t o_off  = aln(o_part + (size_t)nblk_scan * 4); // int[n+1]
  size_t o_cur  = aln(o_off + ((size_t)n + 1) * 4);    // int[n]
  size_t o_csr  = aln(o_cur + (size_t)n * 4);          // int[e]
  size_t o_dinv = aln(o_csr + (size_t)e * 4);          // f32[n]
  size_t o_hn   = aln(o_dinv + (size_t)n * 4);         // f16[(n+1)*64] (+1 zero row)
  size_t o_y    = aln(o_hn + ((size_t)n + 1) * DH * 2);// f32[n*64]
  size_t o_wt0  = aln(o_y + (size_t)n * DH * 4);       // f16[128*64]
  size_t o_wt1  = aln(o_wt0 + 128 * DH * 2);           // f16[64*64]
  size_t o_wt2  = aln(o_wt1 + 64 * DH * 2);            // f16[64*64]
  size_t o_ss   = aln(o_wt2 + 64 * DH * 2);            // f32[3*128]
  int*   degi  = (int*)  (ws + o_degi);
  float* S     = (float*)(ws + o_S);
  int*   part  = (int*)  (ws + o_part);
  int*   off   = (int*)  (ws + o_off);
  int*   cur   = (int*)  (ws + o_cur);
  int*   csr   = (int*)  (ws + o_csr);
  float* dinv  = (float*)(ws + o_dinv);
  f16*   hn    = (f16*)  (ws + o_hn);
  float* y     = (float*)(ws + o_y);
  f16*   wt0   = (f16*)  (ws + o_wt0);
  f16*   wt1   = (f16*)  (ws + o_wt1);
  f16*   wt2   = (f16*)  (ws + o_wt2);
  float* ss    = (float*)(ws + o_ss);

  // Zero degi + BN-stat accumulators in one memset (adjacent).
  hipMemsetAsync(ws, 0, o_part, stream);

  // Weight transpose+fp16 + zero hn[n] row (tiny, once, single launch).
  k_wprep<<<(128 * DH + 255) / 256, 256, 0, stream>>>(W0, W1, W2, wt0, wt1, wt2,
                                                      hn + (size_t)n * DH);

  // CSR build (once; reused by all 3 layers).
  k_count<<<(e + 255) / 256, 256, 0, stream>>>(dst, degi, e);
  k_scan1<<<nblk_scan, 256, 0, stream>>>(degi, dinv, cur, part, n);
  k_scan2<<<nblk_scan, 256, 0, stream>>>(part, cur, off, n, e);
  k_fill<<<(e + 255) / 256, 256, 0, stream>>>(src, dst, cur, csr, e);

  const int mfma_blocks = (n + 63) / 64;  // 4 waves/block * 16 rows/wave

  // Layer 0
  k_mfma<128, false><<<mfma_blocks, 256, 0, stream>>>(x, wt0, dinv, nullptr, hn, n);
  k_aggbn<<<2048, 256, 0, stream>>>(hn, off, csr, dinv, b0, y, S + 0 * 128, n);
  k_scaleshift<<<1, 64, 0, stream>>>(S + 0 * 128, gamma + 0 * DH, beta + 0 * DH,
                                     ss + 0 * 128, inv_n);
  // Layer 1 (BN+ReLU of layer 0 fused into MFMA A-load)
  k_mfma<64, true><<<mfma_blocks, 256, 0, stream>>>(y, wt1, dinv, ss + 0 * 128, hn, n);
  k_aggbn<<<2048, 256, 0, stream>>>(hn, off, csr, dinv, b1, y, S + 1 * 128, n);
  k_scaleshift<<<1, 64, 0, stream>>>(S + 1 * 128, gamma + 1 * DH, beta + 1 * DH,
                                     ss + 1 * 128, inv_n);
  // Layer 2
  k_mfma<64, true><<<mfma_blocks, 256, 0, stream>>>(y, wt2, dinv, ss + 1 * 128, hn, n);
  k_aggbn<<<2048, 256, 0, stream>>>(hn, off, csr, dinv, b2, y, S + 2 * 128, n);
  k_scaleshift<<<1, 64, 0, stream>>>(S + 2 * 128, gamma + 2 * DH, beta + 2 * DH,
                                     ss + 2 * 128, inv_n);
  // Output projection (BN+ReLU of layer 2 fused)
  k_out<<<512, 256, 0, stream>>>(y, ss + 2 * 128, Wout, bout, out, n);
}